// Round 2
// baseline (84.147 us; speedup 1.0000x reference)
//
#include <hip/hip_runtime.h>
#include <stdint.h>

// MNISTQuant: out[65536,50] = x[65536,784] @ (int8_w[784,50] * scaler)
// Memory-bound (~205 MB x read). Structure: no x-LDS (L1/L2 serves the 4x
// col-chunk reuse of identical A-fragment addresses), register-resident
// dequantized B fragments, depth-3 global->reg prefetch, per-tile output
// staged through small LDS for contiguous float4 stores.

typedef __attribute__((ext_vector_type(8))) short bf16x8;
typedef __attribute__((ext_vector_type(4))) float f32x4;

#define IN_F 784
#define OUT_F 50
#define NSTEP 25              // K padded 784 -> 800 (25 x 32)
#define NTILES 4096           // 65536 rows / 16
#define NBLK 768              // 3 blocks/CU on 256 CUs, grid-stride over tiles
#define NTHREADS 256

__device__ __forceinline__ unsigned short f2bf(float f) {
    unsigned int u = __builtin_bit_cast(unsigned int, f);
    u += 0x7FFFu + ((u >> 16) & 1u);   // round-to-nearest-even
    return (unsigned short)(u >> 16);
}

__global__ __launch_bounds__(NTHREADS, 3) void MNISTQuant_48687749267957_kernel(
    const float* __restrict__ x,
    const int* __restrict__ wq,          // int8 weights delivered as int32
    const float* __restrict__ scaler,
    float* __restrict__ out)
{
    __shared__ float lo[2][16 * OUT_F]; // out-tile staging, double-buffered (6.4 KB)

    const int tid  = threadIdx.x;
    const int lane = tid & 63;
    const int wave = tid >> 6;          // col chunk 0..3
    const int arow = lane & 15;         // A row within tile
    const int kgrp = lane >> 4;         // k sub-chunk (8 elems) within 32-wide step
    const int bcol = wave * 16 + arow;  // output col (>=50 -> discarded)
    const float scl = scaler[0];

    // ---- Prologue: per-wave register B fragments (dequant int8 -> bf16) ----
    // wq is L2-resident (157 KB); clamp addresses for pad cols/k, values there
    // are never used (A zeroed for pad k, pad cols never staged out).
    const int wcol = bcol < OUT_F ? bcol : OUT_F - 1;
    bf16x8 bfrag[NSTEP];
    #pragma unroll
    for (int s = 0; s < NSTEP; ++s) {
        #pragma unroll
        for (int j = 0; j < 8; ++j) {
            const int k  = s * 32 + kgrp * 8 + j;
            const int kk = k < IN_F ? k : IN_F - 1;
            const float w = (float)wq[kk * OUT_F + wcol] * scl;
            bfrag[s][j] = (short)f2bf(w);
        }
    }

    const bf16x8 z8 = {0, 0, 0, 0, 0, 0, 0, 0};

    int it = 0;
    for (int t = blockIdx.x; t < NTILES; t += NBLK, ++it) {
        // lane's x row slice: step s reads 8 floats at s*32 + kgrp*8
        const float* xr = x + (size_t)t * (16 * IN_F) + (size_t)arow * IN_F + kgrp * 8;

        // depth-3 rotating prefetch (indices static under full unroll)
        f32x4 pa[3], pb[3];
        #pragma unroll
        for (int s = 0; s < 3; ++s) {
            pa[s] = *(const f32x4*)(xr + s * 32);
            pb[s] = *(const f32x4*)(xr + s * 32 + 4);
        }

        f32x4 acc0 = {0.f, 0.f, 0.f, 0.f}, acc1 = {0.f, 0.f, 0.f, 0.f};
        #pragma unroll
        for (int s = 0; s < NSTEP; ++s) {
            const int b = s % 3;
            bf16x8 a;
            #pragma unroll
            for (int j = 0; j < 4; ++j) {
                a[j]     = (short)f2bf(pa[b][j]);
                a[j + 4] = (short)f2bf(pb[b][j]);
            }
            // k >= 784 pad: zero this quarter-wave's A at the last step
            if (s == NSTEP - 1 && kgrp >= 2) a = z8;
            // prefetch step s+3 (step 24 only in-bounds for kgrp<2)
            if (s + 3 < NSTEP) {
                if (s + 3 < NSTEP - 1 || kgrp < 2) {
                    pa[b] = *(const f32x4*)(xr + (s + 3) * 32);
                    pb[b] = *(const f32x4*)(xr + (s + 3) * 32 + 4);
                }
            }
            if ((s & 1) == 0)
                acc0 = __builtin_amdgcn_mfma_f32_16x16x32_bf16(a, bfrag[s], acc0, 0, 0, 0);
            else
                acc1 = __builtin_amdgcn_mfma_f32_16x16x32_bf16(a, bfrag[s], acc1, 0, 0, 0);
        }
        const f32x4 acc = acc0 + acc1;

        // ---- stage C tile to LDS, then one contiguous 3200-B float4 write ----
        float* lb = lo[it & 1];
        if (bcol < OUT_F) {
            const int r0 = (lane >> 4) * 4;   // C rows: (lane>>4)*4 + j  [m89 layout]
            #pragma unroll
            for (int j = 0; j < 4; ++j)
                lb[(r0 + j) * OUT_F + bcol] = acc[j];
        }
        __syncthreads();
        if (tid < (16 * OUT_F) / 4) {
            const f32x4 v = *(const f32x4*)&lb[tid * 4];
            *((f32x4*)(out + (size_t)t * (16 * OUT_F)) + tid) = v;
        }
    }
}

extern "C" void kernel_launch(void* const* d_in, const int* in_sizes, int n_in,
                              void* d_out, int out_size, void* d_ws, size_t ws_size,
                              hipStream_t stream) {
    const float* x      = (const float*)d_in[0];
    const int*   wq     = (const int*)d_in[1];
    const float* scaler = (const float*)d_in[2];
    float*       out    = (float*)d_out;
    MNISTQuant_48687749267957_kernel<<<NBLK, NTHREADS, 0, stream>>>(x, wq, scaler, out);
}